// Round 12
// baseline (176.943 us; speedup 1.0000x reference)
//
#include <hip/hip_runtime.h>
#include <hip/hip_bf16.h>
#include <stdint.h>

// Problem constants
#define TLEN 2048
#define NHEAD 16
#define CD 1024
#define HDIM 64

typedef __attribute__((ext_vector_type(4))) float f32x4;
typedef __attribute__((ext_vector_type(8))) short s16x8;
typedef __attribute__((ext_vector_type(8))) unsigned short u16x8;
typedef __attribute__((ext_vector_type(4))) unsigned short u16x4;
typedef __attribute__((ext_vector_type(2))) unsigned int u32x2;

typedef __attribute__((address_space(1))) const unsigned int global_u32;
typedef __attribute__((address_space(3))) unsigned int lds_u32;

__device__ __forceinline__ void gl_lds16(const void* g, void* l) {
  __builtin_amdgcn_global_load_lds((global_u32*)g, (lds_u32*)l, 16, 0, 0);
}

__device__ __forceinline__ unsigned short f2bf(float x) {
  unsigned int u = __float_as_uint(x);
  u += 0x7fffu + ((u >> 16) & 1u);   // RTNE; inputs finite
  return (unsigned short)(u >> 16);
}

__device__ __forceinline__ f32x4 mfma_bf16(s16x8 a, s16x8 b, f32x4 c) {
  return __builtin_amdgcn_mfma_f32_16x16x32_bf16(a, b, c, 0, 0, 0);
}

__device__ __forceinline__ float max3f(float a, float b, float c) {
  float d;
  asm("v_max3_f32 %0, %1, %2, %3" : "=v"(d) : "v"(a), "v"(b), "v"(c));
  return d;
}

__device__ __forceinline__ unsigned int pk2bf(float a, float b) {
  __hip_bfloat162 h = __float22bfloat162_rn(make_float2(a, b));
  return *reinterpret_cast<unsigned int*>(&h);
}

// ---------------- fp32 -> bf16 cast, merged (X | Wq | Wo) ----------------
__global__ __launch_bounds__(256) void cvt_all(
    const float* __restrict__ X, const float* __restrict__ Wq,
    const float* __restrict__ Wo, unsigned short* __restrict__ Xb,
    unsigned short* __restrict__ Wqb, unsigned short* __restrict__ Wob) {
  int blk = blockIdx.x;
  const float* src;
  unsigned short* dst;
  int base;
  if (blk < 4096) { src = X;  dst = Xb;  base = blk; }
  else if (blk < 5632) { src = Wq; dst = Wqb; base = blk - 4096; }
  else { src = Wo; dst = Wob; base = blk - 5632; }
  int i = (base * 256 + threadIdx.x) * 8;
  float4 a = *(const float4*)(src + i);
  float4 b = *(const float4*)(src + i + 4);
  u16x8 o;
  o[0] = f2bf(a.x); o[1] = f2bf(a.y); o[2] = f2bf(a.z); o[3] = f2bf(a.w);
  o[4] = f2bf(b.x); o[5] = f2bf(b.y); o[6] = f2bf(b.z); o[7] = f2bf(b.w);
  *(u16x8*)(dst + i) = o;
}

// ---------------- GEMM: C[M][N] = A[M][K] * Bw[N][K]^T + bias ----------------
#define BM 128
#define BN 128
#define BKG 64

template <int SPLIT>
__global__ __launch_bounds__(256) void gemm_bt(
    const unsigned short* __restrict__ A, const unsigned short* __restrict__ Bw,
    const float* __restrict__ bias, float* __restrict__ Cf,
    unsigned short* __restrict__ qk_out, unsigned short* __restrict__ vt_out,
    int M, int N, int K) {
  __shared__ char lds[(BM + BN) * BKG * 2];   // 32 KiB
  char* aL = lds;
  char* bL = lds + BM * BKG * 2;
  const int tid = threadIdx.x;
  const int w = tid >> 6, l = tid & 63, l15 = l & 15, l4 = l >> 4;
  const int wr = w >> 1, wc = w & 1;

  // T1: XCD-aware flat swizzle (nwg % 8 == 0 for both launches)
  const int nbx = gridDim.x;
  const int nwg = nbx * gridDim.y;
  int f = blockIdx.y * nbx + blockIdx.x;
  f = (f & 7) * (nwg >> 3) + (f >> 3);
  const int brow = (f / nbx) * BM, bcol = (f % nbx) * BN;

  f32x4 z4 = {0.f, 0.f, 0.f, 0.f};
  f32x4 acc[4][4];
#pragma unroll
  for (int m = 0; m < 4; ++m)
#pragma unroll
    for (int n = 0; n < 4; ++n) acc[m][n] = z4;

  const unsigned short* Ab = A + (size_t)brow * K;
  const unsigned short* Bb = Bw + (size_t)bcol * K;

  for (int k0 = 0; k0 < K; k0 += BKG) {
    __syncthreads();
#pragma unroll
    for (int i = 0; i < 4; ++i) {
      int ch = i * 256 + tid;
      int r = ch >> 3, c = ch & 7;
      int cs = (c ^ (r & 7)) * 8;
      gl_lds16(Ab + (size_t)r * K + k0 + cs, aL + ch * 16);
      gl_lds16(Bb + (size_t)r * K + k0 + cs, bL + ch * 16);
    }
    __syncthreads();
#pragma unroll
    for (int kk = 0; kk < 2; ++kk) {
      s16x8 af[4], bfr[4];
#pragma unroll
      for (int m = 0; m < 4; ++m) {
        int r = wr * 64 + m * 16 + l15;
        af[m] = *(const s16x8*)(aL + r * (BKG * 2) +
                                ((kk * 64 + l4 * 16) ^ ((r & 7) << 4)));
      }
#pragma unroll
      for (int n = 0; n < 4; ++n) {
        int r = wc * 64 + n * 16 + l15;
        bfr[n] = *(const s16x8*)(bL + r * (BKG * 2) +
                                 ((kk * 64 + l4 * 16) ^ ((r & 7) << 4)));
      }
#pragma unroll
      for (int m = 0; m < 4; ++m)
#pragma unroll
        for (int n = 0; n < 4; ++n) acc[m][n] = mfma_bf16(af[m], bfr[n], acc[m][n]);
    }
  }

#pragma unroll
  for (int m = 0; m < 4; ++m) {
    int row0 = brow + wr * 64 + m * 16 + l4 * 4;
#pragma unroll
    for (int n = 0; n < 4; ++n) {
      int col = bcol + wc * 64 + n * 16 + l15;
      float bs = bias[col];
      if (SPLIT == 0) {
#pragma unroll
        for (int r = 0; r < 4; ++r)
          Cf[(size_t)(row0 + r) * N + col] = acc[m][n][r] + bs;
      } else {
        if (col < 2 * CD) {
#pragma unroll
          for (int r = 0; r < 4; ++r)
            qk_out[(size_t)(row0 + r) * (2 * CD) + col] = f2bf(acc[m][n][r] + bs);
        } else {
          int cc = col - 2 * CD;
          int b_ = row0 >> 11;
          int t = row0 & (TLEN - 1);
          u16x4 pk;
#pragma unroll
          for (int r = 0; r < 4; ++r) pk[r] = f2bf(acc[m][n][r] + bs);
          *(u16x4*)(vt_out + (size_t)(b_ * CD + cc) * TLEN + t) = pk;
        }
      }
    }
  }
}

// ---------------- flash attention (KVBLK=128, 32 KB LDS) ---------------------
// 2048 blocks (one q-tile each, longest-first), XCD decode: 8 bh per XCD L2.
// KV tile = 128: longest block 17 iters (was 33) -> per-iter barrier/waitcnt
// overhead amortized 2x. K tile [128kv][128B] (16KB, P aliases it after
// BAR(c)); V^T tile [64d][256B] (16KB, chunk-XOR swizzle (chunk^(d&7))).
// K/V reg-staged (T14), next tile's 8 loads issue right after the ds_writes.
// Swapped S^T = mfma(K,Q): lane q=l15, kv = kt*128 + 16n+4*l4+r (n=0..7).
__global__ __launch_bounds__(256, 4) void attn_fwd(
    const unsigned short* __restrict__ qk,   // [B*T][2048] bf16: Q | K
    const unsigned short* __restrict__ vt,   // [B*H*64][2048] = V^T per head
    unsigned short* __restrict__ ctx) {      // [B*T][1024]
  __shared__ char k_lds[128 * 128];         // K tile; re-used as P after BAR(c)
  __shared__ char v_lds[64 * 256];          // V^T tile, swizzled

  const int fblk = blockIdx.y * 32 + blockIdx.x;
  const int xcd = fblk & 7;
  const int bhi = (fblk >> 3) & 7;
  const int qi = 31 - (fblk >> 6);           // longest blocks dispatch first
  const int bh = xcd * 8 + bhi;
  const int b = bh >> 4, h = bh & 15;
  const int tid = threadIdx.x;
  const int w = tid >> 6, l = tid & 63, l15 = l & 15, l4 = l >> 4;
  const int nt = (qi >> 1) + 1;              // 128-wide kv tiles

  const unsigned short* Kg = qk + (size_t)b * TLEN * (2 * CD) + CD + h * HDIM;
  const unsigned short* Vg = vt + (size_t)bh * HDIM * TLEN;

  const float SC2 = 0.18033688011112042f;   // (1/sqrt(64)) * log2(e)
  char* pw = k_lds + w * 4096;              // wave-private P slice (alias)

  // ---- loop-invariant address registers ----
  const int sw = (l15 & 7) << 4;
  const int cA = (l4 * 16) ^ sw;            // K read, d-chunk 0
  const int cB = (64 + l4 * 16) ^ sw;       // K read, d-chunk 1
  const int row128 = l15 * 128;
  const int prow = l15 * 256;               // P row (256B)
  // P read (4 kc) / write (8 n) offsets within pw
  int prd[4], pwr[8];
#pragma unroll
  for (int kc = 0; kc < 4; ++kc) prd[kc] = prow + ((kc * 64 + l4 * 16) ^ sw);
#pragma unroll
  for (int n = 0; n < 8; ++n) pwr[n] = prow + ((n * 32 + l4 * 8) ^ sw);
  // V read: row byte l15*256 + dc*4096 + voff[kc]
  int voff[4];
#pragma unroll
  for (int kc = 0; kc < 4; ++kc) voff[kc] = ((kc * 4 + l4) ^ (l15 & 7)) << 4;
  const int vrow = l15 * 256;
  // staging: thread owns chunks {i*256+tid}, i=0..3, for both K and V
  const int ldso0 = tid * 16;               // + i*4096
  const char* gkb = (const char*)Kg + (tid >> 3) * 4096 +
                    (((tid & 7) ^ ((tid >> 3) & 7)) << 4);
  const char* gvb = (const char*)Vg + (tid >> 4) * 4096 +
                    (((tid & 15) ^ ((tid >> 4) & 7)) << 4);
  const int bperm_addr = (l ^ 32) << 2;

  s16x8 onesf;                              // bf16 1.0 broadcast B-fragment
#pragma unroll
  for (int j = 0; j < 8; ++j) onesf[j] = (short)0x3F80;

  f32x4 z4 = {0.f, 0.f, 0.f, 0.f};

  // Q fragments (B-operand): col q = l15, k: d = l4*8 + j
  const unsigned short* qrow =
      qk + (size_t)(b * TLEN + qi * 64 + w * 16 + l15) * (2 * CD) + h * HDIM;
  s16x8 qf0 = *(const s16x8*)(qrow + l4 * 8);
  s16x8 qf1 = *(const s16x8*)(qrow + 32 + l4 * 8);

  f32x4 acc_o[4];
#pragma unroll
  for (int dc = 0; dc < 4; ++dc) acc_o[dc] = z4;
  f32x4 acc_l = z4;                         // softmax denominator (ones-MFMA)
  float m_r = -3.0e38f;
  const int qg = w * 16 + l15;              // q within the 64-row q-tile

  // prologue: K(0), V(0) -> regs (8 x 16B loads)
  s16x8 kst0 = *(const s16x8*)(gkb);
  s16x8 kst1 = *(const s16x8*)(gkb + 131072);
  s16x8 kst2 = *(const s16x8*)(gkb + 262144);
  s16x8 kst3 = *(const s16x8*)(gkb + 393216);
  s16x8 vst0 = *(const s16x8*)(gvb);
  s16x8 vst1 = *(const s16x8*)(gvb + 65536);
  s16x8 vst2 = *(const s16x8*)(gvb + 131072);
  s16x8 vst3 = *(const s16x8*)(gvb + 196608);

  for (int kt = 0; kt < nt; ++kt) {
    __builtin_amdgcn_s_barrier();           // BAR(a): all LDS reads of t-1 done
    __builtin_amdgcn_sched_barrier(0);
    asm volatile("s_waitcnt vmcnt(0)" ::: "memory");  // staging regs ready
    // K(t), V(t): regs -> LDS (K overwrites dead P(t-1))
    *(s16x8*)(k_lds + ldso0)         = kst0;
    *(s16x8*)(k_lds + ldso0 + 4096)  = kst1;
    *(s16x8*)(k_lds + ldso0 + 8192)  = kst2;
    *(s16x8*)(k_lds + ldso0 + 12288) = kst3;
    *(s16x8*)(v_lds + ldso0)         = vst0;
    *(s16x8*)(v_lds + ldso0 + 4096)  = vst1;
    *(s16x8*)(v_lds + ldso0 + 8192)  = vst2;
    *(s16x8*)(v_lds + ldso0 + 12288) = vst3;
    if (kt + 1 < nt) {                      // issue K/V(t+1) -> regs (early)
      gkb += 524288; gvb += 256;
      kst0 = *(const s16x8*)(gkb);
      kst1 = *(const s16x8*)(gkb + 131072);
      kst2 = *(const s16x8*)(gkb + 262144);
      kst3 = *(const s16x8*)(gkb + 393216);
      vst0 = *(const s16x8*)(gvb);
      vst1 = *(const s16x8*)(gvb + 65536);
      vst2 = *(const s16x8*)(gvb + 131072);
      vst3 = *(const s16x8*)(gvb + 196608);
    }
    asm volatile("s_waitcnt lgkmcnt(0)" ::: "memory");  // ds_writes landed
    __builtin_amdgcn_sched_barrier(0);
    __builtin_amdgcn_s_barrier();           // BAR(b): K(t)+V(t) visible
    __builtin_amdgcn_sched_barrier(0);

    const char* ka0 = k_lds + row128 + cA;
    const char* ka1 = k_lds + row128 + cB;

    // S^T = K Q^T : lane q = l15, kv = kt*128 + n*16 + l4*4 + r (n=0..7)
    f32x4 s[8];
    __builtin_amdgcn_s_setprio(1);
#pragma unroll
    for (int n = 0; n < 8; ++n) {
      s16x8 kf0 = *(const s16x8*)(ka0 + n * 2048);
      s16x8 kf1 = *(const s16x8*)(ka1 + n * 2048);
      f32x4 z = z4;
      z = mfma_bf16(kf0, qf0, z);
      z = mfma_bf16(kf1, qf1, z);
      s[n] = z;
    }
    __builtin_amdgcn_s_setprio(0);

    if (kt == nt - 1) {                     // causal mask on the last tile
      int kvb = kt * 128 + l4 * 4 - (qi * 64 + qg);
#pragma unroll
      for (int n = 0; n < 8; ++n)
#pragma unroll
        for (int r = 0; r < 4; ++r)
          if (kvb + n * 16 + r > 0) s[n][r] = -3.0e38f;
    }

    // in-lane partial max over this lane's 32 kv values (max3 tree)
    float t[8];
#pragma unroll
    for (int n = 0; n < 8; ++n)
      t[n] = fmaxf(max3f(s[n][0], s[n][1], s[n][2]), s[n][3]);
    float tm = max3f(max3f(t[0], t[1], t[2]), max3f(t[3], t[4], t[5]),
                     fmaxf(t[6], t[7]));
    tm = fmaxf(tm, __shfl_xor(tm, 16));
    tm = fmaxf(tm, __int_as_float(__builtin_amdgcn_ds_bpermute(
                       bperm_addr, __float_as_int(tm))));

    __builtin_amdgcn_s_barrier();           // BAR(c): all K-reads done ->
    __builtin_amdgcn_sched_barrier(0);      //         k_lds free for P

    // defer-max (T13): only rescale when the max grew by more than THR
    if (!__all((tm - m_r) * SC2 <= 8.0f)) {
      float m_n = fmaxf(m_r, tm);
      float corr = __builtin_amdgcn_exp2f((m_r - m_n) * SC2);
      m_r = m_n;
      *(float*)(pw + l15 * 4) = corr;       // wave-private scratch
      asm volatile("s_waitcnt lgkmcnt(0)" ::: "memory");
      __builtin_amdgcn_sched_barrier(0);
      float corr4[4];
#pragma unroll
      for (int r = 0; r < 4; ++r)
        corr4[r] = *(const float*)(pw + (l4 * 4 + r) * 4);
#pragma unroll
      for (int r = 0; r < 4; ++r) {
        acc_l[r] *= corr4[r];
#pragma unroll
        for (int dc = 0; dc < 4; ++dc) acc_o[dc][r] *= corr4[r];
      }
    }

    // P = exp2(s*SC2 - m*SC2), bounded by 2^8 -> RTNE pack -> b64 writes
    float msc = m_r * SC2;
#pragma unroll
    for (int n = 0; n < 8; ++n) {
      float p0 = __builtin_amdgcn_exp2f(fmaf(s[n][0], SC2, -msc));
      float p1 = __builtin_amdgcn_exp2f(fmaf(s[n][1], SC2, -msc));
      float p2 = __builtin_amdgcn_exp2f(fmaf(s[n][2], SC2, -msc));
      float p3 = __builtin_amdgcn_exp2f(fmaf(s[n][3], SC2, -msc));
      u32x2 pr;
      pr[0] = pk2bf(p0, p1);
      pr[1] = pk2bf(p2, p3);
      *(u32x2*)(pw + pwr[n]) = pr;
    }

    // P writes are wave-private; DS pipe is in-order per wave, just drain
    asm volatile("s_waitcnt lgkmcnt(0)" ::: "memory");
    __builtin_amdgcn_sched_barrier(0);

    // O += P V ; denominator += P * ones
    __builtin_amdgcn_s_setprio(1);
#pragma unroll
    for (int kc = 0; kc < 4; ++kc) {
      s16x8 pf = *(const s16x8*)(pw + prd[kc]);
      acc_l = mfma_bf16(pf, onesf, acc_l);
#pragma unroll
      for (int dc = 0; dc < 4; ++dc) {
        s16x8 vf = *(const s16x8*)(v_lds + vrow + dc * 4096 + voff[kc]);
        acc_o[dc] = mfma_bf16(pf, vf, acc_o[dc]);
      }
    }
    __builtin_amdgcn_s_setprio(0);
  }

  // normalize + write ctx (bf16)
#pragma unroll
  for (int r = 0; r < 4; ++r) {
    int qgl = qi * 64 + w * 16 + l4 * 4 + r;
    float inv = 1.0f / acc_l[r];
    size_t base = (size_t)(b * TLEN + qgl) * CD + h * HDIM;
#pragma unroll
    for (int dc = 0; dc < 4; ++dc)
      ctx[base + dc * 16 + l15] = f2bf(acc_o[dc][r] * inv);
  }
}

// ---------------- launch ----------------
extern "C" void kernel_launch(void* const* d_in, const int* in_sizes, int n_in,
                              void* d_out, int out_size, void* d_ws, size_t ws_size,
                              hipStream_t stream) {
  const float* X  = (const float*)d_in[0];   // [4,2048,1024]
  const float* Wq = (const float*)d_in[1];   // [3072,1024]
  const float* bq = (const float*)d_in[2];   // [3072]
  const float* Wo = (const float*)d_in[3];   // [1024,1024]
  const float* bo = (const float*)d_in[4];   // [1024]
  float* out = (float*)d_out;

  char* ws = (char*)d_ws;
  unsigned short* Xb  = (unsigned short*)ws;                       // 16.78 MB
  unsigned short* Wqb = (unsigned short*)(ws + 16777216);          //  6.29 MB
  unsigned short* Wob = (unsigned short*)(ws + 23068672);          //  2.10 MB
  unsigned short* QK  = (unsigned short*)(ws + 25165824);          // 33.55 MB
  unsigned short* Vt  = (unsigned short*)(ws + 58720256);          // 16.78 MB
  unsigned short* Ctx = Xb;   // alias: Xb dead after QKV GEMM     // total 75.5 MB

  cvt_all<<<6144, 256, 0, stream>>>(X, Wq, Wo, Xb, Wqb, Wob);

  gemm_bt<1><<<dim3(24, 64), 256, 0, stream>>>(Xb, Wqb, bq, nullptr, QK, Vt,
                                               8192, 3072, 1024);
  attn_fwd<<<dim3(32, 64), 256, 0, stream>>>(QK, Vt, Ctx);
  gemm_bt<0><<<dim3(8, 64), 256, 0, stream>>>(Ctx, Wob, bo, out, nullptr, nullptr,
                                              8192, 1024, 1024);
}

// Round 13
// 173.483 us; speedup vs baseline: 1.0199x; 1.0199x over previous
//
#include <hip/hip_runtime.h>
#include <hip/hip_bf16.h>
#include <stdint.h>

// Problem constants
#define TLEN 2048
#define NHEAD 16
#define CD 1024
#define HDIM 64

typedef __attribute__((ext_vector_type(4))) float f32x4;
typedef __attribute__((ext_vector_type(8))) short s16x8;
typedef __attribute__((ext_vector_type(8))) unsigned short u16x8;
typedef __attribute__((ext_vector_type(4))) unsigned short u16x4;
typedef __attribute__((ext_vector_type(2))) unsigned int u32x2;

typedef __attribute__((address_space(1))) const unsigned int global_u32;
typedef __attribute__((address_space(3))) unsigned int lds_u32;

__device__ __forceinline__ void gl_lds16(const void* g, void* l) {
  __builtin_amdgcn_global_load_lds((global_u32*)g, (lds_u32*)l, 16, 0, 0);
}

__device__ __forceinline__ unsigned short f2bf(float x) {
  unsigned int u = __float_as_uint(x);
  u += 0x7fffu + ((u >> 16) & 1u);   // RTNE; inputs finite
  return (unsigned short)(u >> 16);
}

__device__ __forceinline__ f32x4 mfma_bf16(s16x8 a, s16x8 b, f32x4 c) {
  return __builtin_amdgcn_mfma_f32_16x16x32_bf16(a, b, c, 0, 0, 0);
}

__device__ __forceinline__ float max3f(float a, float b, float c) {
  float d;
  asm("v_max3_f32 %0, %1, %2, %3" : "=v"(d) : "v"(a), "v"(b), "v"(c));
  return d;
}

__device__ __forceinline__ unsigned int pk2bf(float a, float b) {
  __hip_bfloat162 h = __float22bfloat162_rn(make_float2(a, b));
  return *reinterpret_cast<unsigned int*>(&h);
}

// ---------------- fp32 -> bf16 cast, merged (X | Wq | Wo) ----------------
__global__ __launch_bounds__(256) void cvt_all(
    const float* __restrict__ X, const float* __restrict__ Wq,
    const float* __restrict__ Wo, unsigned short* __restrict__ Xb,
    unsigned short* __restrict__ Wqb, unsigned short* __restrict__ Wob) {
  int blk = blockIdx.x;
  const float* src;
  unsigned short* dst;
  int base;
  if (blk < 4096) { src = X;  dst = Xb;  base = blk; }
  else if (blk < 5632) { src = Wq; dst = Wqb; base = blk - 4096; }
  else { src = Wo; dst = Wob; base = blk - 5632; }
  int i = (base * 256 + threadIdx.x) * 8;
  float4 a = *(const float4*)(src + i);
  float4 b = *(const float4*)(src + i + 4);
  u16x8 o;
  o[0] = f2bf(a.x); o[1] = f2bf(a.y); o[2] = f2bf(a.z); o[3] = f2bf(a.w);
  o[4] = f2bf(b.x); o[5] = f2bf(b.y); o[6] = f2bf(b.z); o[7] = f2bf(b.w);
  *(u16x8*)(dst + i) = o;
}

// ---------------- GEMM: C[M][N] = A[M][K] * Bw[N][K]^T + bias ----------------
#define BM 128
#define BN 128
#define BKG 64

template <int SPLIT>
__global__ __launch_bounds__(256) void gemm_bt(
    const unsigned short* __restrict__ A, const unsigned short* __restrict__ Bw,
    const float* __restrict__ bias, float* __restrict__ Cf,
    unsigned short* __restrict__ qk_out, unsigned short* __restrict__ vt_out,
    int M, int N, int K) {
  __shared__ char lds[(BM + BN) * BKG * 2];   // 32 KiB
  char* aL = lds;
  char* bL = lds + BM * BKG * 2;
  const int tid = threadIdx.x;
  const int w = tid >> 6, l = tid & 63, l15 = l & 15, l4 = l >> 4;
  const int wr = w >> 1, wc = w & 1;

  // T1: XCD-aware flat swizzle (nwg % 8 == 0 for both launches)
  const int nbx = gridDim.x;
  const int nwg = nbx * gridDim.y;
  int f = blockIdx.y * nbx + blockIdx.x;
  f = (f & 7) * (nwg >> 3) + (f >> 3);
  const int brow = (f / nbx) * BM, bcol = (f % nbx) * BN;

  f32x4 z4 = {0.f, 0.f, 0.f, 0.f};
  f32x4 acc[4][4];
#pragma unroll
  for (int m = 0; m < 4; ++m)
#pragma unroll
    for (int n = 0; n < 4; ++n) acc[m][n] = z4;

  const unsigned short* Ab = A + (size_t)brow * K;
  const unsigned short* Bb = Bw + (size_t)bcol * K;

  for (int k0 = 0; k0 < K; k0 += BKG) {
    __syncthreads();
#pragma unroll
    for (int i = 0; i < 4; ++i) {
      int ch = i * 256 + tid;
      int r = ch >> 3, c = ch & 7;
      int cs = (c ^ (r & 7)) * 8;
      gl_lds16(Ab + (size_t)r * K + k0 + cs, aL + ch * 16);
      gl_lds16(Bb + (size_t)r * K + k0 + cs, bL + ch * 16);
    }
    __syncthreads();
#pragma unroll
    for (int kk = 0; kk < 2; ++kk) {
      s16x8 af[4], bfr[4];
#pragma unroll
      for (int m = 0; m < 4; ++m) {
        int r = wr * 64 + m * 16 + l15;
        af[m] = *(const s16x8*)(aL + r * (BKG * 2) +
                                ((kk * 64 + l4 * 16) ^ ((r & 7) << 4)));
      }
#pragma unroll
      for (int n = 0; n < 4; ++n) {
        int r = wc * 64 + n * 16 + l15;
        bfr[n] = *(const s16x8*)(bL + r * (BKG * 2) +
                                 ((kk * 64 + l4 * 16) ^ ((r & 7) << 4)));
      }
#pragma unroll
      for (int m = 0; m < 4; ++m)
#pragma unroll
        for (int n = 0; n < 4; ++n) acc[m][n] = mfma_bf16(af[m], bfr[n], acc[m][n]);
    }
  }

#pragma unroll
  for (int m = 0; m < 4; ++m) {
    int row0 = brow + wr * 64 + m * 16 + l4 * 4;
#pragma unroll
    for (int n = 0; n < 4; ++n) {
      int col = bcol + wc * 64 + n * 16 + l15;
      float bs = bias[col];
      if (SPLIT == 0) {
#pragma unroll
        for (int r = 0; r < 4; ++r)
          Cf[(size_t)(row0 + r) * N + col] = acc[m][n][r] + bs;
      } else {
        if (col < 2 * CD) {
#pragma unroll
          for (int r = 0; r < 4; ++r)
            qk_out[(size_t)(row0 + r) * (2 * CD) + col] = f2bf(acc[m][n][r] + bs);
        } else {
          int cc = col - 2 * CD;
          int b_ = row0 >> 11;
          int t = row0 & (TLEN - 1);
          u16x4 pk;
#pragma unroll
          for (int r = 0; r < 4; ++r) pk[r] = f2bf(acc[m][n][r] + bs);
          *(u16x4*)(vt_out + (size_t)(b_ * CD + cc) * TLEN + t) = pk;
        }
      }
    }
  }
}

// ---------------- flash attention (R8 config + RTNE pack + max3) -------------
// 2048 blocks (one q-tile each, longest-first), XCD decode: 8 bh per XCD L2.
// K and V both reg-staged (T14). Single 8KB LDS buffer each. P ALIASES k_lds:
// BAR(c) after the max-reduce guarantees all waves' QK K-reads are done
// before any P write; BAR(a) guarantees all PV P-reads are done before the
// next K ds_write. Swapped S^T = mfma(K,Q) in-register softmax, defer-max.
// NOTE: VGPR=64 here is load-bearing — 8 waves/SIMD (m69 cliff at 64).
__global__ __launch_bounds__(256) void attn_fwd(
    const unsigned short* __restrict__ qk,   // [B*T][2048] bf16: Q | K
    const unsigned short* __restrict__ vt,   // [B*H*64][2048] = V^T per head
    unsigned short* __restrict__ ctx) {      // [B*T][1024]
  __shared__ char k_lds[64 * 128];          // K tile; re-used as P after BAR(c)
  __shared__ char v_lds[64 * 128];          // V^T tile [d][kv], swizzled

  const int fblk = blockIdx.y * 32 + blockIdx.x;
  const int xcd = fblk & 7;
  const int bhi = (fblk >> 3) & 7;
  const int qi = 31 - (fblk >> 6);           // longest blocks dispatch first
  const int bh = xcd * 8 + bhi;
  const int b = bh >> 4, h = bh & 15;
  const int tid = threadIdx.x;
  const int w = tid >> 6, l = tid & 63, l15 = l & 15, l4 = l >> 4;
  const int nt = qi + 1;

  const unsigned short* Kg = qk + (size_t)b * TLEN * (2 * CD) + CD + h * HDIM;
  const unsigned short* Vg = vt + (size_t)bh * HDIM * TLEN;

  const float SC2 = 0.18033688011112042f;   // (1/sqrt(64)) * log2(e)
  char* pw = k_lds + w * 2048;              // wave-private P slice (alias)

  // ---- loop-invariant address registers ----
  const int sw = (l15 & 7) << 4;
  const int c0 = (l4 * 16) ^ sw;
  const int c1 = (64 + l4 * 16) ^ sw;
  const int row128 = l15 * 128;
  const char* prd0 = pw + row128 + c0;
  const char* prd1 = pw + row128 + c1;
  char* pwr0 = pw + row128 + ((0 * 32 + l4 * 8) ^ sw);
  char* pwr1 = pw + row128 + ((1 * 32 + l4 * 8) ^ sw);
  char* pwr2 = pw + row128 + ((2 * 32 + l4 * 8) ^ sw);
  char* pwr3 = pw + row128 + ((3 * 32 + l4 * 8) ^ sw);
  const int ch0 = tid, ch1 = 256 + tid;
  const int ldsoff0 = ch0 * 16, ldsoff1 = ch1 * 16;
  const int r0 = ch0 >> 3, r1 = ch1 >> 3;
  const int cs0 = ((ch0 & 7) ^ (r0 & 7)) * 8;
  const int cs1 = ((ch1 & 7) ^ (r1 & 7)) * 8;
  const int bperm_addr = (l ^ 32) << 2;

  s16x8 onesf;                              // bf16 1.0 broadcast B-fragment
#pragma unroll
  for (int j = 0; j < 8; ++j) onesf[j] = (short)0x3F80;

  f32x4 z4 = {0.f, 0.f, 0.f, 0.f};

  // Q fragments (B-operand): col q = l15, k: d = l4*8 + j
  const unsigned short* qrow =
      qk + (size_t)(b * TLEN + qi * 64 + w * 16 + l15) * (2 * CD) + h * HDIM;
  s16x8 qf0 = *(const s16x8*)(qrow + l4 * 8);
  s16x8 qf1 = *(const s16x8*)(qrow + 32 + l4 * 8);

  f32x4 acc_o[4];
#pragma unroll
  for (int dc = 0; dc < 4; ++dc) acc_o[dc] = z4;
  f32x4 acc_l = z4;                         // softmax denominator (ones-MFMA)
  float m_r = -3.0e38f;

  // running global staging pointers (bytes), tile 0
  const char* gk0 = (const char*)Kg + r0 * 4096 + cs0 * 2;
  const char* gk1 = (const char*)Kg + r1 * 4096 + cs1 * 2;
  const char* gv0 = (const char*)Vg + r0 * 4096 + cs0 * 2;
  const char* gv1 = (const char*)Vg + r1 * 4096 + cs1 * 2;

  // prologue: K(0), V(0) -> regs
  s16x8 kstg0 = *(const s16x8*)gk0;
  s16x8 kstg1 = *(const s16x8*)gk1;
  s16x8 vstg0 = *(const s16x8*)gv0;
  s16x8 vstg1 = *(const s16x8*)gv1;

  for (int kt = 0; kt < nt; ++kt) {
    __builtin_amdgcn_s_barrier();           // BAR(a): all LDS reads of t-1 done
    __builtin_amdgcn_sched_barrier(0);
    asm volatile("s_waitcnt vmcnt(0)" ::: "memory");  // staging regs ready
    // K(t), V(t): regs -> LDS (single buffers; K overwrites dead P(t-1))
    *(s16x8*)(k_lds + ldsoff0) = kstg0;
    *(s16x8*)(k_lds + ldsoff1) = kstg1;
    *(s16x8*)(v_lds + ldsoff0) = vstg0;
    *(s16x8*)(v_lds + ldsoff1) = vstg1;
    if (kt + 1 < nt) {                      // issue K/V(t+1) -> regs (early)
      gk0 += 262144; gk1 += 262144; gv0 += 128; gv1 += 128;
      kstg0 = *(const s16x8*)gk0;
      kstg1 = *(const s16x8*)gk1;
      vstg0 = *(const s16x8*)gv0;
      vstg1 = *(const s16x8*)gv1;
    }
    asm volatile("s_waitcnt lgkmcnt(0)" ::: "memory");  // ds_writes landed
    __builtin_amdgcn_sched_barrier(0);
    __builtin_amdgcn_s_barrier();           // BAR(b): K(t)+V(t) visible
    __builtin_amdgcn_sched_barrier(0);

    const char* ka0 = k_lds + row128 + c0;
    const char* ka1 = k_lds + row128 + c1;

    // S^T = K Q^T : lane q = l15, kv = n*16 + l4*4 + r
    f32x4 s[4];
    __builtin_amdgcn_s_setprio(1);
#pragma unroll
    for (int n = 0; n < 4; ++n) {
      s16x8 kf0 = *(const s16x8*)(ka0 + n * 2048);
      s16x8 kf1 = *(const s16x8*)(ka1 + n * 2048);
      f32x4 z = z4;
      z = mfma_bf16(kf0, qf0, z);
      z = mfma_bf16(kf1, qf1, z);
      s[n] = z;
    }
    __builtin_amdgcn_s_setprio(0);

    if (kt == qi) {                         // causal mask, diagonal tile only
      int ql = w * 16 + l15;
#pragma unroll
      for (int n = 0; n < 4; ++n)
#pragma unroll
        for (int r = 0; r < 4; ++r)
          if ((n * 16 + l4 * 4 + r) > ql) s[n][r] = -3.0e38f;
    }

    // in-lane partial max over this lane's 16 kv values (max3 tree)
    float t0 = fmaxf(max3f(s[0][0], s[0][1], s[0][2]), s[0][3]);
    float t1 = fmaxf(max3f(s[1][0], s[1][1], s[1][2]), s[1][3]);
    float t2 = fmaxf(max3f(s[2][0], s[2][1], s[2][2]), s[2][3]);
    float t3 = fmaxf(max3f(s[3][0], s[3][1], s[3][2]), s[3][3]);
    float tm = fmaxf(max3f(t0, t1, t2), t3);
    tm = fmaxf(tm, __shfl_xor(tm, 16));
    tm = fmaxf(tm, __int_as_float(__builtin_amdgcn_ds_bpermute(
                       bperm_addr, __float_as_int(tm))));

    __builtin_amdgcn_s_barrier();           // BAR(c): all K-reads done ->
    __builtin_amdgcn_sched_barrier(0);      //         k_lds free for P

    // defer-max (T13): only rescale when the max grew by more than THR
    if (!__all((tm - m_r) * SC2 <= 8.0f)) {
      float m_n = fmaxf(m_r, tm);
      float corr = __builtin_amdgcn_exp2f((m_r - m_n) * SC2);
      m_r = m_n;
      *(float*)(pw + 256 + l15 * 4) = corr;
      asm volatile("s_waitcnt lgkmcnt(0)" ::: "memory");
      __builtin_amdgcn_sched_barrier(0);
      float corr4[4];
#pragma unroll
      for (int r = 0; r < 4; ++r)
        corr4[r] = *(const float*)(pw + 256 + (l4 * 4 + r) * 4);
#pragma unroll
      for (int r = 0; r < 4; ++r) {
        acc_l[r] *= corr4[r];
#pragma unroll
        for (int dc = 0; dc < 4; ++dc) acc_o[dc][r] *= corr4[r];
      }
    }

    // P = exp2(s*SC2 - m*SC2) -> RTNE packed bf16 (R12-verified) -> b64
    float msc = m_r * SC2;
#pragma unroll
    for (int n = 0; n < 4; ++n) {
      float p0 = __builtin_amdgcn_exp2f(fmaf(s[n][0], SC2, -msc));
      float p1 = __builtin_amdgcn_exp2f(fmaf(s[n][1], SC2, -msc));
      float p2 = __builtin_amdgcn_exp2f(fmaf(s[n][2], SC2, -msc));
      float p3 = __builtin_amdgcn_exp2f(fmaf(s[n][3], SC2, -msc));
      u32x2 pr;
      pr[0] = pk2bf(p0, p1);
      pr[1] = pk2bf(p2, p3);
      char* dst = (n == 0) ? pwr0 : (n == 1) ? pwr1 : (n == 2) ? pwr2 : pwr3;
      *(u32x2*)dst = pr;
    }

    // P writes are wave-private; DS pipe is in-order per wave, just drain
    asm volatile("s_waitcnt lgkmcnt(0)" ::: "memory");
    __builtin_amdgcn_sched_barrier(0);

    // O += P V ; denominator += P * ones
    __builtin_amdgcn_s_setprio(1);
    {
      s16x8 pf0 = *(const s16x8*)prd0;
      s16x8 pf1 = *(const s16x8*)prd1;
      acc_l = mfma_bf16(pf0, onesf, acc_l);
      acc_l = mfma_bf16(pf1, onesf, acc_l);
#pragma unroll
      for (int dc = 0; dc < 4; ++dc) {
        s16x8 vf0 = *(const s16x8*)(v_lds + dc * 2048 + row128 + c0);
        s16x8 vf1 = *(const s16x8*)(v_lds + dc * 2048 + row128 + c1);
        acc_o[dc] = mfma_bf16(pf0, vf0, acc_o[dc]);
        acc_o[dc] = mfma_bf16(pf1, vf1, acc_o[dc]);
      }
    }
    __builtin_amdgcn_s_setprio(0);
  }

  // normalize + write ctx (bf16)
#pragma unroll
  for (int r = 0; r < 4; ++r) {
    int qg = qi * 64 + w * 16 + l4 * 4 + r;
    float inv = 1.0f / acc_l[r];
    size_t base = (size_t)(b * TLEN + qg) * CD + h * HDIM;
#pragma unroll
    for (int dc = 0; dc < 4; ++dc)
      ctx[base + dc * 16 + l15] = f2bf(acc_o[dc][r] * inv);
  }
}

// ---------------- launch ----------------
extern "C" void kernel_launch(void* const* d_in, const int* in_sizes, int n_in,
                              void* d_out, int out_size, void* d_ws, size_t ws_size,
                              hipStream_t stream) {
  const float* X  = (const float*)d_in[0];   // [4,2048,1024]
  const float* Wq = (const float*)d_in[1];   // [3072,1024]
  const float* bq = (const float*)d_in[2];   // [3072]
  const float* Wo = (const float*)d_in[3];   // [1024,1024]
  const float* bo = (const float*)d_in[4];   // [1024]
  float* out = (float*)d_out;

  char* ws = (char*)d_ws;
  unsigned short* Xb  = (unsigned short*)ws;                       // 16.78 MB
  unsigned short* Wqb = (unsigned short*)(ws + 16777216);          //  6.29 MB
  unsigned short* Wob = (unsigned short*)(ws + 23068672);          //  2.10 MB
  unsigned short* QK  = (unsigned short*)(ws + 25165824);          // 33.55 MB
  unsigned short* Vt  = (unsigned short*)(ws + 58720256);          // 16.78 MB
  unsigned short* Ctx = Xb;   // alias: Xb dead after QKV GEMM     // total 75.5 MB

  cvt_all<<<6144, 256, 0, stream>>>(X, Wq, Wo, Xb, Wqb, Wob);

  gemm_bt<1><<<dim3(24, 64), 256, 0, stream>>>(Xb, Wqb, bq, nullptr, QK, Vt,
                                               8192, 3072, 1024);
  attn_fwd<<<dim3(32, 64), 256, 0, stream>>>(QK, Vt, Ctx);
  gemm_bt<0><<<dim3(8, 64), 256, 0, stream>>>(Ctx, Wob, bo, out, nullptr, nullptr,
                                              8192, 1024, 1024);
}

// Round 14
// 171.772 us; speedup vs baseline: 1.0301x; 1.0100x over previous
//
#include <hip/hip_runtime.h>
#include <hip/hip_bf16.h>
#include <stdint.h>

// Problem constants
#define TLEN 2048
#define NHEAD 16
#define CD 1024
#define HDIM 64

typedef __attribute__((ext_vector_type(4))) float f32x4;
typedef __attribute__((ext_vector_type(8))) short s16x8;
typedef __attribute__((ext_vector_type(8))) unsigned short u16x8;
typedef __attribute__((ext_vector_type(4))) unsigned short u16x4;
typedef __attribute__((ext_vector_type(2))) unsigned int u32x2;

typedef __attribute__((address_space(1))) const unsigned int global_u32;
typedef __attribute__((address_space(3))) unsigned int lds_u32;

__device__ __forceinline__ void gl_lds16(const void* g, void* l) {
  __builtin_amdgcn_global_load_lds((global_u32*)g, (lds_u32*)l, 16, 0, 0);
}

__device__ __forceinline__ unsigned short f2bf(float x) {
  unsigned int u = __float_as_uint(x);
  u += 0x7fffu + ((u >> 16) & 1u);   // RTNE; inputs finite
  return (unsigned short)(u >> 16);
}

__device__ __forceinline__ f32x4 mfma_bf16(s16x8 a, s16x8 b, f32x4 c) {
  return __builtin_amdgcn_mfma_f32_16x16x32_bf16(a, b, c, 0, 0, 0);
}

// ---------------- fp32 -> bf16 cast, merged (X | Wq | Wo) ----------------
__global__ __launch_bounds__(256) void cvt_all(
    const float* __restrict__ X, const float* __restrict__ Wq,
    const float* __restrict__ Wo, unsigned short* __restrict__ Xb,
    unsigned short* __restrict__ Wqb, unsigned short* __restrict__ Wob) {
  int blk = blockIdx.x;
  const float* src;
  unsigned short* dst;
  int base;
  if (blk < 4096) { src = X;  dst = Xb;  base = blk; }
  else if (blk < 5632) { src = Wq; dst = Wqb; base = blk - 4096; }
  else { src = Wo; dst = Wob; base = blk - 5632; }
  int i = (base * 256 + threadIdx.x) * 8;
  float4 a = *(const float4*)(src + i);
  float4 b = *(const float4*)(src + i + 4);
  u16x8 o;
  o[0] = f2bf(a.x); o[1] = f2bf(a.y); o[2] = f2bf(a.z); o[3] = f2bf(a.w);
  o[4] = f2bf(b.x); o[5] = f2bf(b.y); o[6] = f2bf(b.z); o[7] = f2bf(b.w);
  *(u16x8*)(dst + i) = o;
}

// ---------------- GEMM: C[M][N] = A[M][K] * Bw[N][K]^T + bias ----------------
#define BM 128
#define BN 128
#define BKG 64

template <int SPLIT>
__global__ __launch_bounds__(256) void gemm_bt(
    const unsigned short* __restrict__ A, const unsigned short* __restrict__ Bw,
    const float* __restrict__ bias, float* __restrict__ Cf,
    unsigned short* __restrict__ qk_out, unsigned short* __restrict__ vt_out,
    int M, int N, int K) {
  __shared__ char lds[(BM + BN) * BKG * 2];   // 32 KiB
  char* aL = lds;
  char* bL = lds + BM * BKG * 2;
  const int tid = threadIdx.x;
  const int w = tid >> 6, l = tid & 63, l15 = l & 15, l4 = l >> 4;
  const int wr = w >> 1, wc = w & 1;

  // T1: XCD-aware flat swizzle (nwg % 8 == 0 for both launches)
  const int nbx = gridDim.x;
  const int nwg = nbx * gridDim.y;
  int f = blockIdx.y * nbx + blockIdx.x;
  f = (f & 7) * (nwg >> 3) + (f >> 3);
  const int brow = (f / nbx) * BM, bcol = (f % nbx) * BN;

  f32x4 z4 = {0.f, 0.f, 0.f, 0.f};
  f32x4 acc[4][4];
#pragma unroll
  for (int m = 0; m < 4; ++m)
#pragma unroll
    for (int n = 0; n < 4; ++n) acc[m][n] = z4;

  const unsigned short* Ab = A + (size_t)brow * K;
  const unsigned short* Bb = Bw + (size_t)bcol * K;

  for (int k0 = 0; k0 < K; k0 += BKG) {
    __syncthreads();
#pragma unroll
    for (int i = 0; i < 4; ++i) {
      int ch = i * 256 + tid;
      int r = ch >> 3, c = ch & 7;
      int cs = (c ^ (r & 7)) * 8;
      gl_lds16(Ab + (size_t)r * K + k0 + cs, aL + ch * 16);
      gl_lds16(Bb + (size_t)r * K + k0 + cs, bL + ch * 16);
    }
    __syncthreads();
#pragma unroll
    for (int kk = 0; kk < 2; ++kk) {
      s16x8 af[4], bfr[4];
#pragma unroll
      for (int m = 0; m < 4; ++m) {
        int r = wr * 64 + m * 16 + l15;
        af[m] = *(const s16x8*)(aL + r * (BKG * 2) +
                                ((kk * 64 + l4 * 16) ^ ((r & 7) << 4)));
      }
#pragma unroll
      for (int n = 0; n < 4; ++n) {
        int r = wc * 64 + n * 16 + l15;
        bfr[n] = *(const s16x8*)(bL + r * (BKG * 2) +
                                 ((kk * 64 + l4 * 16) ^ ((r & 7) << 4)));
      }
#pragma unroll
      for (int m = 0; m < 4; ++m)
#pragma unroll
        for (int n = 0; n < 4; ++n) acc[m][n] = mfma_bf16(af[m], bfr[n], acc[m][n]);
    }
  }

#pragma unroll
  for (int m = 0; m < 4; ++m) {
    int row0 = brow + wr * 64 + m * 16 + l4 * 4;
#pragma unroll
    for (int n = 0; n < 4; ++n) {
      int col = bcol + wc * 64 + n * 16 + l15;
      float bs = bias[col];
      if (SPLIT == 0) {
#pragma unroll
        for (int r = 0; r < 4; ++r)
          Cf[(size_t)(row0 + r) * N + col] = acc[m][n][r] + bs;
      } else {
        if (col < 2 * CD) {
#pragma unroll
          for (int r = 0; r < 4; ++r)
            qk_out[(size_t)(row0 + r) * (2 * CD) + col] = f2bf(acc[m][n][r] + bs);
        } else {
          int cc = col - 2 * CD;
          int b_ = row0 >> 11;
          int t = row0 & (TLEN - 1);
          u16x4 pk;
#pragma unroll
          for (int r = 0; r < 4; ++r) pk[r] = f2bf(acc[m][n][r] + bs);
          *(u16x4*)(vt_out + (size_t)(b_ * CD + cc) * TLEN + t) = pk;
        }
      }
    }
  }
}

// ---------------- flash attention (R11 + separate P buffer, 2 barriers) ------
// 2048 blocks (one q-tile each, longest-first), XCD decode: 8 bh per XCD L2.
// K and V both reg-staged (T14), single 8KB LDS buffer each. P has its OWN
// 8KB buffer (LDS 24KB -> 6 blocks/CU, >= measured ~3-4 avg residency) which
// removes BAR(c): P is wave-private so K-reads never race P-writes; the K/V
// overwrite at t+1 is fenced by BAR(a). 2 barriers/iter.
// Swapped S^T = mfma(K,Q) in-register softmax, defer-max (T13).
// NOTE: VGPR=64 is load-bearing — 8 waves/SIMD (m69 cliff at 64).
__global__ __launch_bounds__(256) void attn_fwd(
    const unsigned short* __restrict__ qk,   // [B*T][2048] bf16: Q | K
    const unsigned short* __restrict__ vt,   // [B*H*64][2048] = V^T per head
    unsigned short* __restrict__ ctx) {      // [B*T][1024]
  __shared__ char k_lds[64 * 128];          // K tile [kv][d], swizzled
  __shared__ char v_lds[64 * 128];          // V^T tile [d][kv], swizzled
  __shared__ char p_lds[4 * 16 * 128];      // per-wave P [16 q][64 kv], swizzled

  const int fblk = blockIdx.y * 32 + blockIdx.x;
  const int xcd = fblk & 7;
  const int bhi = (fblk >> 3) & 7;
  const int qi = 31 - (fblk >> 6);           // longest blocks dispatch first
  const int bh = xcd * 8 + bhi;
  const int b = bh >> 4, h = bh & 15;
  const int tid = threadIdx.x;
  const int w = tid >> 6, l = tid & 63, l15 = l & 15, l4 = l >> 4;
  const int nt = qi + 1;

  const unsigned short* Kg = qk + (size_t)b * TLEN * (2 * CD) + CD + h * HDIM;
  const unsigned short* Vg = vt + (size_t)bh * HDIM * TLEN;

  const float SC2 = 0.18033688011112042f;   // (1/sqrt(64)) * log2(e)
  char* pw = p_lds + w * 2048;              // wave-private P slice

  // ---- loop-invariant address registers ----
  const int sw = (l15 & 7) << 4;
  const int c0 = (l4 * 16) ^ sw;
  const int c1 = (64 + l4 * 16) ^ sw;
  const int row128 = l15 * 128;
  const char* prd0 = pw + row128 + c0;
  const char* prd1 = pw + row128 + c1;
  char* pwr0 = pw + row128 + ((0 * 32 + l4 * 8) ^ sw);
  char* pwr1 = pw + row128 + ((1 * 32 + l4 * 8) ^ sw);
  char* pwr2 = pw + row128 + ((2 * 32 + l4 * 8) ^ sw);
  char* pwr3 = pw + row128 + ((3 * 32 + l4 * 8) ^ sw);
  const int ch0 = tid, ch1 = 256 + tid;
  const int ldsoff0 = ch0 * 16, ldsoff1 = ch1 * 16;
  const int r0 = ch0 >> 3, r1 = ch1 >> 3;
  const int cs0 = ((ch0 & 7) ^ (r0 & 7)) * 8;
  const int cs1 = ((ch1 & 7) ^ (r1 & 7)) * 8;
  const int bperm_addr = (l ^ 32) << 2;

  s16x8 onesf;                              // bf16 1.0 broadcast B-fragment
#pragma unroll
  for (int j = 0; j < 8; ++j) onesf[j] = (short)0x3F80;

  f32x4 z4 = {0.f, 0.f, 0.f, 0.f};

  // Q fragments (B-operand): col q = l15, k: d = l4*8 + j
  const unsigned short* qrow =
      qk + (size_t)(b * TLEN + qi * 64 + w * 16 + l15) * (2 * CD) + h * HDIM;
  s16x8 qf0 = *(const s16x8*)(qrow + l4 * 8);
  s16x8 qf1 = *(const s16x8*)(qrow + 32 + l4 * 8);

  f32x4 acc_o[4];
#pragma unroll
  for (int dc = 0; dc < 4; ++dc) acc_o[dc] = z4;
  f32x4 acc_l = z4;                         // softmax denominator (ones-MFMA)
  float m_r = -3.0e38f;

  // running global staging pointers (bytes), tile 0
  const char* gk0 = (const char*)Kg + r0 * 4096 + cs0 * 2;
  const char* gk1 = (const char*)Kg + r1 * 4096 + cs1 * 2;
  const char* gv0 = (const char*)Vg + r0 * 4096 + cs0 * 2;
  const char* gv1 = (const char*)Vg + r1 * 4096 + cs1 * 2;

  // prologue: K(0), V(0) -> regs
  s16x8 kstg0 = *(const s16x8*)gk0;
  s16x8 kstg1 = *(const s16x8*)gk1;
  s16x8 vstg0 = *(const s16x8*)gv0;
  s16x8 vstg1 = *(const s16x8*)gv1;

  for (int kt = 0; kt < nt; ++kt) {
    __builtin_amdgcn_s_barrier();           // BAR(a): all LDS reads of t-1 done
    __builtin_amdgcn_sched_barrier(0);
    asm volatile("s_waitcnt vmcnt(0)" ::: "memory");  // staging regs ready
    // K(t), V(t): regs -> LDS (single buffers)
    *(s16x8*)(k_lds + ldsoff0) = kstg0;
    *(s16x8*)(k_lds + ldsoff1) = kstg1;
    *(s16x8*)(v_lds + ldsoff0) = vstg0;
    *(s16x8*)(v_lds + ldsoff1) = vstg1;
    if (kt + 1 < nt) {                      // issue K/V(t+1) -> regs (early)
      gk0 += 262144; gk1 += 262144; gv0 += 128; gv1 += 128;
      kstg0 = *(const s16x8*)gk0;
      kstg1 = *(const s16x8*)gk1;
      vstg0 = *(const s16x8*)gv0;
      vstg1 = *(const s16x8*)gv1;
    }
    asm volatile("s_waitcnt lgkmcnt(0)" ::: "memory");  // ds_writes landed
    __builtin_amdgcn_sched_barrier(0);
    __builtin_amdgcn_s_barrier();           // BAR(b): K(t)+V(t) visible
    __builtin_amdgcn_sched_barrier(0);

    const char* ka0 = k_lds + row128 + c0;
    const char* ka1 = k_lds + row128 + c1;

    // S^T = K Q^T : lane q = l15, kv = n*16 + l4*4 + r
    f32x4 s[4];
    __builtin_amdgcn_s_setprio(1);
#pragma unroll
    for (int n = 0; n < 4; ++n) {
      s16x8 kf0 = *(const s16x8*)(ka0 + n * 2048);
      s16x8 kf1 = *(const s16x8*)(ka1 + n * 2048);
      f32x4 z = z4;
      z = mfma_bf16(kf0, qf0, z);
      z = mfma_bf16(kf1, qf1, z);
      s[n] = z;
    }
    __builtin_amdgcn_s_setprio(0);

    if (kt == qi) {                         // causal mask, diagonal tile only
      int ql = w * 16 + l15;
#pragma unroll
      for (int n = 0; n < 4; ++n)
#pragma unroll
        for (int r = 0; r < 4; ++r)
          if ((n * 16 + l4 * 4 + r) > ql) s[n][r] = -3.0e38f;
    }

    // in-lane partial max over this lane's 16 kv values
    float t0 = fmaxf(fmaxf(s[0][0], s[0][1]), fmaxf(s[0][2], s[0][3]));
    float t1 = fmaxf(fmaxf(s[1][0], s[1][1]), fmaxf(s[1][2], s[1][3]));
    float t2 = fmaxf(fmaxf(s[2][0], s[2][1]), fmaxf(s[2][2], s[2][3]));
    float t3 = fmaxf(fmaxf(s[3][0], s[3][1]), fmaxf(s[3][2], s[3][3]));
    float tm = fmaxf(fmaxf(t0, t1), fmaxf(t2, t3));
    tm = fmaxf(tm, __shfl_xor(tm, 16));
    tm = fmaxf(tm, __int_as_float(__builtin_amdgcn_ds_bpermute(
                       bperm_addr, __float_as_int(tm))));

    // defer-max (T13): only rescale when the max grew by more than THR
    if (!__all((tm - m_r) * SC2 <= 8.0f)) {
      float m_n = fmaxf(m_r, tm);
      float corr = __builtin_amdgcn_exp2f((m_r - m_n) * SC2);
      m_r = m_n;
      *(float*)(pw + 256 + l15 * 4) = corr;  // wave-private scratch
      asm volatile("s_waitcnt lgkmcnt(0)" ::: "memory");
      __builtin_amdgcn_sched_barrier(0);
      float corr4[4];
#pragma unroll
      for (int r = 0; r < 4; ++r)
        corr4[r] = *(const float*)(pw + 256 + (l4 * 4 + r) * 4);
#pragma unroll
      for (int r = 0; r < 4; ++r) {
        acc_l[r] *= corr4[r];
#pragma unroll
        for (int dc = 0; dc < 4; ++dc) acc_o[dc][r] *= corr4[r];
      }
    }

    // P = exp2(s*SC2 - m*SC2), bounded by 2^8 -> truncation pack -> b64
    float msc = m_r * SC2;
#pragma unroll
    for (int n = 0; n < 4; ++n) {
      float p0 = __builtin_amdgcn_exp2f(fmaf(s[n][0], SC2, -msc));
      float p1 = __builtin_amdgcn_exp2f(fmaf(s[n][1], SC2, -msc));
      float p2 = __builtin_amdgcn_exp2f(fmaf(s[n][2], SC2, -msc));
      float p3 = __builtin_amdgcn_exp2f(fmaf(s[n][3], SC2, -msc));
      u32x2 pr;
      pr[0] = (__float_as_uint(p1) & 0xffff0000u) | (__float_as_uint(p0) >> 16);
      pr[1] = (__float_as_uint(p3) & 0xffff0000u) | (__float_as_uint(p2) >> 16);
      char* dst = (n == 0) ? pwr0 : (n == 1) ? pwr1 : (n == 2) ? pwr2 : pwr3;
      *(u32x2*)dst = pr;
    }

    // P writes are wave-private; DS pipe is in-order per wave, just drain
    asm volatile("s_waitcnt lgkmcnt(0)" ::: "memory");
    __builtin_amdgcn_sched_barrier(0);

    // O += P V ; denominator += P * ones
    __builtin_amdgcn_s_setprio(1);
    {
      s16x8 pf0 = *(const s16x8*)prd0;
      s16x8 pf1 = *(const s16x8*)prd1;
      acc_l = mfma_bf16(pf0, onesf, acc_l);
      acc_l = mfma_bf16(pf1, onesf, acc_l);
#pragma unroll
      for (int dc = 0; dc < 4; ++dc) {
        s16x8 vf0 = *(const s16x8*)(v_lds + dc * 2048 + row128 + c0);
        s16x8 vf1 = *(const s16x8*)(v_lds + dc * 2048 + row128 + c1);
        acc_o[dc] = mfma_bf16(pf0, vf0, acc_o[dc]);
        acc_o[dc] = mfma_bf16(pf1, vf1, acc_o[dc]);
      }
    }
    __builtin_amdgcn_s_setprio(0);
  }

  // normalize + write ctx (bf16)
#pragma unroll
  for (int r = 0; r < 4; ++r) {
    int qg = qi * 64 + w * 16 + l4 * 4 + r;
    float inv = 1.0f / acc_l[r];
    size_t base = (size_t)(b * TLEN + qg) * CD + h * HDIM;
#pragma unroll
    for (int dc = 0; dc < 4; ++dc)
      ctx[base + dc * 16 + l15] = f2bf(acc_o[dc][r] * inv);
  }
}

// ---------------- launch ----------------
extern "C" void kernel_launch(void* const* d_in, const int* in_sizes, int n_in,
                              void* d_out, int out_size, void* d_ws, size_t ws_size,
                              hipStream_t stream) {
  const float* X  = (const float*)d_in[0];   // [4,2048,1024]
  const float* Wq = (const float*)d_in[1];   // [3072,1024]
  const float* bq = (const float*)d_in[2];   // [3072]
  const float* Wo = (const float*)d_in[3];   // [1024,1024]
  const float* bo = (const float*)d_in[4];   // [1024]
  float* out = (float*)d_out;

  char* ws = (char*)d_ws;
  unsigned short* Xb  = (unsigned short*)ws;                       // 16.78 MB
  unsigned short* Wqb = (unsigned short*)(ws + 16777216);          //  6.29 MB
  unsigned short* Wob = (unsigned short*)(ws + 23068672);          //  2.10 MB
  unsigned short* QK  = (unsigned short*)(ws + 25165824);          // 33.55 MB
  unsigned short* Vt  = (unsigned short*)(ws + 58720256);          // 16.78 MB
  unsigned short* Ctx = Xb;   // alias: Xb dead after QKV GEMM     // total 75.5 MB

  cvt_all<<<6144, 256, 0, stream>>>(X, Wq, Wo, Xb, Wqb, Wob);

  gemm_bt<1><<<dim3(24, 64), 256, 0, stream>>>(Xb, Wqb, bq, nullptr, QK, Vt,
                                               8192, 3072, 1024);
  attn_fwd<<<dim3(32, 64), 256, 0, stream>>>(QK, Vt, Ctx);
  gemm_bt<0><<<dim3(8, 64), 256, 0, stream>>>(Ctx, Wob, bo, out, nullptr, nullptr,
                                              8192, 1024, 1024);
}